// Round 5
// baseline (459.312 us; speedup 1.0000x reference)
//
#include <hip/hip_runtime.h>

// (B,T,D,H,KD)=(8,1024,512,8,64), SIGMA=1.
// d_out: out [8*1024*512] f32, then attn_weights S [64][1024][1024] f32.
// R5: pre-split fp32 inputs to bf16 hi/lo (split out of GEMM inner loop),
// one merged projection launch (3072 blocks, BK=64, q2/k2 fused into the
// epilogue), flash with nontemporal S stores.  Pre-split scratch lives in
// the S output region (flash overwrites it afterwards).

typedef float  floatx4 __attribute__((ext_vector_type(4)));
typedef short  short8  __attribute__((ext_vector_type(8)));
typedef unsigned short ushort_t;
typedef unsigned short ushort4v __attribute__((ext_vector_type(4)));

#define MFMA16(a, b, c) __builtin_amdgcn_mfma_f32_16x16x32_bf16((a), (b), (c), 0, 0, 0)

__device__ inline ushort_t f2b(float f) {  // f32 -> bf16 bits, RNE
    unsigned u = __builtin_bit_cast(unsigned, f);
    unsigned r = u + 0x7fffu + ((u >> 16) & 1u);
    return (ushort_t)(r >> 16);
}
__device__ inline ushort_t f2b_trunc(float f) {
    return (ushort_t)(__builtin_bit_cast(unsigned, f) >> 16);
}
__device__ inline float b2f(ushort_t s) {
    return __builtin_bit_cast(float, (unsigned)s << 16);
}

// Async global->LDS, 16B/lane.  LDS dest = wave-uniform base + lane*16.
__device__ inline void gl_lds16(const void* g, void* l) {
    __builtin_amdgcn_global_load_lds(
        (const __attribute__((address_space(1))) unsigned int*)g,
        (__attribute__((address_space(3))) unsigned int*)l, 16, 0, 0);
}

// ---------------------------------------------------------------------------
// Weight transpose + split: WT[n][k] = W[k][n]; hi=bf16(w), lo=bf16(w-hi).
// ---------------------------------------------------------------------------
__global__ __launch_bounds__(256) void wt_cvt(
    const float* __restrict__ Wq, const float* __restrict__ Wk,
    const float* __restrict__ Wv, const float* __restrict__ Wo,
    ushort_t* __restrict__ qTh, ushort_t* __restrict__ qTl,
    ushort_t* __restrict__ kTh, ushort_t* __restrict__ kTl,
    ushort_t* __restrict__ vT,  ushort_t* __restrict__ oT)
{
    const int idx = blockIdx.x * 256 + threadIdx.x;  // n*512+k
    const int n = idx >> 9, k = idx & 511;
    const float* W; ushort_t* H; ushort_t* L; bool wl;
    switch (blockIdx.y) {
        case 0:  W = Wq; H = qTh; L = qTl; wl = true;  break;
        case 1:  W = Wk; H = kTh; L = kTl; wl = true;  break;
        case 2:  W = Wv; H = vT;  L = vT;  wl = false; break;
        default: W = Wo; H = oT;  L = oT;  wl = false; break;
    }
    float f = W[(size_t)k * 512 + n];
    ushort_t h = f2b(f);
    H[idx] = h;
    if (wl) L[idx] = f2b(f - b2f(h));
}

// ---------------------------------------------------------------------------
// Pre-split: query/key fp32 -> bf16 hi+lo; value fp32 -> bf16.
// Bit-identical to the former in-loop split, done once instead of 8x.
// ---------------------------------------------------------------------------
__global__ __launch_bounds__(256) void presplit(
    const float* __restrict__ q, const float* __restrict__ k,
    const float* __restrict__ v,
    ushort_t* __restrict__ qxh, ushort_t* __restrict__ qxl,
    ushort_t* __restrict__ kxh, ushort_t* __restrict__ kxl,
    ushort_t* __restrict__ vx)
{
    const int i = blockIdx.x * 256 + threadIdx.x;  // float4 index, 0..1048575
    float4 qv = ((const float4*)q)[i];
    float4 kv = ((const float4*)k)[i];
    float4 vv = ((const float4*)v)[i];
    float qa[4] = {qv.x, qv.y, qv.z, qv.w};
    float ka[4] = {kv.x, kv.y, kv.z, kv.w};
    float va[4] = {vv.x, vv.y, vv.z, vv.w};
    ushort4v qh4, ql4, kh4, kl4, vb4;
#pragma unroll
    for (int j = 0; j < 4; ++j) {
        ushort_t qh = f2b(qa[j]); qh4[j] = qh; ql4[j] = f2b(qa[j] - b2f(qh));
        ushort_t kh = f2b(ka[j]); kh4[j] = kh; kl4[j] = f2b(ka[j] - b2f(kh));
        vb4[j] = f2b(va[j]);
    }
    ((ushort4v*)qxh)[i] = qh4;
    ((ushort4v*)qxl)[i] = ql4;
    ((ushort4v*)kxh)[i] = kh4;
    ((ushort4v*)kxl)[i] = kl4;
    ((ushort4v*)vx)[i]  = vb4;
}

// ---------------------------------------------------------------------------
// Merged projection GEMM, grid 3072.  mode = gid>>10: 0=q (3-pass split,
// out hi/lo + q2), 1=k (same -> k2), 2=v (1-pass, out vhT[z][d][T]).
// Tile 64x64, BK=64 (8 iters, 24 or 8 MFMA per barrier pair), LDS staging
// via global_load_lds w=16 with XOR chunk swizzle.  q2/k2 computed from the
// fp32 accumulator via 16-lane shuffle reduce (block's 64 cols = one head).
// ---------------------------------------------------------------------------
__global__ __launch_bounds__(256) void proj_all(
    const ushort_t* __restrict__ qxh, const ushort_t* __restrict__ qxl,
    const ushort_t* __restrict__ kxh, const ushort_t* __restrict__ kxl,
    const ushort_t* __restrict__ vx,
    const ushort_t* __restrict__ WqTh, const ushort_t* __restrict__ WqTl,
    const ushort_t* __restrict__ WkTh, const ushort_t* __restrict__ WkTl,
    const ushort_t* __restrict__ WvT,
    ushort_t* __restrict__ qh_hi, ushort_t* __restrict__ qh_lo,
    ushort_t* __restrict__ kh_hi, ushort_t* __restrict__ kh_lo,
    ushort_t* __restrict__ vhT, float* __restrict__ q2, float* __restrict__ k2)
{
    __shared__ __align__(16) ushort_t sAh[64 * 64];
    __shared__ __align__(16) ushort_t sAl[64 * 64];
    __shared__ __align__(16) ushort_t sBh[64 * 64];
    __shared__ __align__(16) ushort_t sBl[64 * 64];

    const int tid = threadIdx.x;
    const int w = tid >> 6, lane = tid & 63;
    const int l15 = lane & 15, quad = lane >> 4;
    const int gid = blockIdx.x;
    const int mode = gid >> 10, g = gid & 1023;
    const int m0 = (g >> 3) * 64, n0 = (g & 7) * 64;

    const ushort_t *Ah, *Al, *Bh, *Bl;
    if (mode == 0)      { Ah = qxh; Al = qxl; Bh = WqTh; Bl = WqTl; }
    else if (mode == 1) { Ah = kxh; Al = kxl; Bh = WkTh; Bl = WkTl; }
    else                { Ah = vx;  Al = vx;  Bh = WvT;  Bl = WvT;  }
    const bool split = (mode < 2);

    floatx4 acc[4];
#pragma unroll
    for (int i = 0; i < 4; ++i) acc[i] = (floatx4){0.f, 0.f, 0.f, 0.f};

    for (int it = 0; it < 8; ++it) {
        const int k0 = it * 64;
        // ---- stage (64x64 bf16 = 8KB per tile, 2 chunks/lane) ----
#pragma unroll
        for (int t = 0; t < 2; ++t) {
            const int c = (w * 2 + t) * 64 + lane;
            const int row = c >> 3, kch = ((c & 7) - row) & 7;
            const size_t ao = (size_t)(m0 + row) * 512 + k0 + kch * 8;
            const size_t bo = (size_t)(n0 + row) * 512 + k0 + kch * 8;
            const int ldst = (w * 2 + t) * 1024;
            gl_lds16(Ah + ao, (char*)sAh + ldst);
            gl_lds16(Bh + bo, (char*)sBh + ldst);
            if (split) {
                gl_lds16(Al + ao, (char*)sAl + ldst);
                gl_lds16(Bl + bo, (char*)sBl + ldst);
            }
        }
        __syncthreads();

        // ---- fragments + MFMAs (compiler interleaves) ----
        const int ra = 16 * w + l15;
        short8 ah[2], al[2];
#pragma unroll
        for (int h2 = 0; h2 < 2; ++h2) {
            const int off = ra * 64 + ((quad + h2 * 4 + ra) & 7) * 8;
            ah[h2] = *(const short8*)&sAh[off];
            if (split) al[h2] = *(const short8*)&sAl[off];
        }
#pragma unroll
        for (int ni = 0; ni < 4; ++ni) {
            const int rb = ni * 16 + l15;
#pragma unroll
            for (int h2 = 0; h2 < 2; ++h2) {
                const int off = rb * 64 + ((quad + h2 * 4 + rb) & 7) * 8;
                short8 bh = *(const short8*)&sBh[off];
                acc[ni] = MFMA16(ah[h2], bh, acc[ni]);
                if (split) {
                    short8 bl = *(const short8*)&sBl[off];
                    acc[ni] = MFMA16(al[h2], bh, acc[ni]);
                    acc[ni] = MFMA16(ah[h2], bl, acc[ni]);
                }
            }
        }
        __syncthreads();
    }

    // ---- epilogue ----
    if (mode == 2) {
        const int hh = n0 >> 6;
#pragma unroll
        for (int ni = 0; ni < 4; ++ni) {
            const int d = ni * 16 + l15;
#pragma unroll
            for (int r = 0; r < 4; ++r) {
                const int m = m0 + 16 * w + quad * 4 + r;
                const int b = m >> 10, t = m & 1023;
                vhT[((size_t)(b * 8 + hh) * 64 + d) * 1024 + t] = f2b(acc[ni][r]);
            }
        }
    } else {
        ushort_t* OH = mode ? kh_hi : qh_hi;
        ushort_t* OL = mode ? kh_lo : qh_lo;
        float* NRM   = mode ? k2 : q2;
#pragma unroll
        for (int ni = 0; ni < 4; ++ni) {
            const int n = n0 + ni * 16 + l15;
#pragma unroll
            for (int r = 0; r < 4; ++r) {
                const int m = m0 + 16 * w + quad * 4 + r;
                const float v = acc[ni][r];
                ushort_t h = f2b(v);
                OH[(size_t)m * 512 + n] = h;
                OL[(size_t)m * 512 + n] = f2b(v - b2f(h));
            }
        }
        // per-row squared norm over this block's 64 cols (= one head)
        float s4[4];
#pragma unroll
        for (int r = 0; r < 4; ++r) {
            float s = 0.f;
#pragma unroll
            for (int ni = 0; ni < 4; ++ni) s = fmaf(acc[ni][r], acc[ni][r], s);
            s += __shfl_xor(s, 1);
            s += __shfl_xor(s, 2);
            s += __shfl_xor(s, 4);
            s += __shfl_xor(s, 8);
            s4[r] = s;
        }
        if (l15 == 0) {
            const int hh = n0 >> 6;
#pragma unroll
            for (int r = 0; r < 4; ++r) {
                const int m = m0 + 16 * w + quad * 4 + r;
                const int b = m >> 10, t = m & 1023;
                NRM[(size_t)(b * 8 + hh) * 1024 + t] = s4[r];
            }
        }
    }
}

// ---------------------------------------------------------------------------
// Output projection: out = attn_bf @ WoT, 1-pass bf16, f32 out.  Same
// skeleton as proj_all mode 2, tile 64x64, BK=64.
// ---------------------------------------------------------------------------
__global__ __launch_bounds__(256) void outproj(
    const ushort_t* __restrict__ Ab, const ushort_t* __restrict__ BTh,
    float* __restrict__ outF)
{
    __shared__ __align__(16) ushort_t sAh[64 * 64];
    __shared__ __align__(16) ushort_t sBh[64 * 64];

    const int tid = threadIdx.x;
    const int w = tid >> 6, lane = tid & 63;
    const int l15 = lane & 15, quad = lane >> 4;
    const int gid = blockIdx.x;
    const int m0 = (gid >> 3) * 64, n0 = (gid & 7) * 64;

    floatx4 acc[4];
#pragma unroll
    for (int i = 0; i < 4; ++i) acc[i] = (floatx4){0.f, 0.f, 0.f, 0.f};

    for (int it = 0; it < 8; ++it) {
        const int k0 = it * 64;
#pragma unroll
        for (int t = 0; t < 2; ++t) {
            const int c = (w * 2 + t) * 64 + lane;
            const int row = c >> 3, kch = ((c & 7) - row) & 7;
            const int ldst = (w * 2 + t) * 1024;
            gl_lds16(Ab + (size_t)(m0 + row) * 512 + k0 + kch * 8, (char*)sAh + ldst);
            gl_lds16(BTh + (size_t)(n0 + row) * 512 + k0 + kch * 8, (char*)sBh + ldst);
        }
        __syncthreads();

        const int ra = 16 * w + l15;
        short8 ah[2];
#pragma unroll
        for (int h2 = 0; h2 < 2; ++h2)
            ah[h2] = *(const short8*)&sAh[ra * 64 + ((quad + h2 * 4 + ra) & 7) * 8];
#pragma unroll
        for (int ni = 0; ni < 4; ++ni) {
            const int rb = ni * 16 + l15;
#pragma unroll
            for (int h2 = 0; h2 < 2; ++h2) {
                short8 bh = *(const short8*)&sBh[rb * 64 + ((quad + h2 * 4 + rb) & 7) * 8];
                acc[ni] = MFMA16(ah[h2], bh, acc[ni]);
            }
        }
        __syncthreads();
    }

#pragma unroll
    for (int ni = 0; ni < 4; ++ni) {
        const int n = n0 + ni * 16 + l15;
#pragma unroll
        for (int r = 0; r < 4; ++r) {
            const int m = m0 + 16 * w + quad * 4 + r;
            outF[(size_t)m * 512 + n] = acc[ni][r];
        }
    }
}

// ---------------------------------------------------------------------------
// Fused flash: block = (z, 64 q-rows); gid%64 = z so gid%8 == z%8 (XCD L2
// locality for K/V).  Per 64-col tile: stage Khi/Klo/V^T (3x8KB, swizzled)
// -> barrier -> QK 3-pass MFMA -> exp -> nontemporal S store + bf16 P to
// per-wave LDS strip -> SV MFMA -> barrier.
// ---------------------------------------------------------------------------
__global__ __launch_bounds__(256) void flash_rbf(
    const ushort_t* __restrict__ qh_hi, const ushort_t* __restrict__ qh_lo,
    const ushort_t* __restrict__ kh_hi, const ushort_t* __restrict__ kh_lo,
    const ushort_t* __restrict__ vhT, const float* __restrict__ q2,
    const float* __restrict__ k2, float* __restrict__ S,
    ushort_t* __restrict__ attn)
{
    __shared__ __align__(16) ushort_t sKh[64 * 64];
    __shared__ __align__(16) ushort_t sKl[64 * 64];
    __shared__ __align__(16) ushort_t sV [64 * 64];
    __shared__ __align__(16) ushort_t P  [64 * 72];

    const int tid = threadIdx.x;
    const int w = tid >> 6, lane = tid & 63;
    const int l15 = lane & 15, quad = lane >> 4;
    const int gid = blockIdx.x;
    const int z = gid & 63, qt = gid >> 6;
    const int b = z >> 3, h = z & 7;
    const int q0 = qt * 64;

    const size_t qrow = (size_t)(b * 1024 + q0 + 16 * w + l15) * 512 + h * 64 + quad * 8;
    short8 aqh[2], aql[2];
    aqh[0] = *(const short8*)(qh_hi + qrow);
    aqh[1] = *(const short8*)(qh_hi + qrow + 32);
    aql[0] = *(const short8*)(qh_lo + qrow);
    aql[1] = *(const short8*)(qh_lo + qrow + 32);

    float q2v[4];
#pragma unroll
    for (int r = 0; r < 4; ++r)
        q2v[r] = q2[(size_t)z * 1024 + q0 + 16 * w + quad * 4 + r];

    floatx4 oacc[4];
#pragma unroll
    for (int i = 0; i < 4; ++i) oacc[i] = (floatx4){0.f, 0.f, 0.f, 0.f};

    const size_t Sz = (size_t)z << 20;

    for (int ct = 0; ct < 16; ++ct) {
        const int col0 = ct * 64;

        // ---- stage K hi/lo + V^T tiles ----
#pragma unroll
        for (int t = 0; t < 2; ++t) {
            const int c = (w * 2 + t) * 64 + lane;
            const int row = c >> 3, dch = ((c & 7) - row) & 7;
            const size_t ke = (size_t)(b * 1024 + col0 + row) * 512 + h * 64 + dch * 8;
            const size_t ve = ((size_t)z * 64 + row) * 1024 + col0 + dch * 8;
            const int ldst = (w * 2 + t) * 1024;
            gl_lds16(kh_hi + ke, (char*)sKh + ldst);
            gl_lds16(kh_lo + ke, (char*)sKl + ldst);
            gl_lds16(vhT + ve,  (char*)sV  + ldst);
        }
        float k2v[4];
#pragma unroll
        for (int j = 0; j < 4; ++j)
            k2v[j] = k2[(size_t)z * 1024 + col0 + j * 16 + l15];
        __syncthreads();

        // ---- QK^T, 3-pass split ----
        floatx4 s[4];
#pragma unroll
        for (int j = 0; j < 4; ++j) {
            const int row = j * 16 + l15;
            const int base = row * 64;
            short8 kh0 = *(const short8*)&sKh[base + ((quad + row) & 7) * 8];
            short8 kh1 = *(const short8*)&sKh[base + ((quad + 4 + row) & 7) * 8];
            short8 kl0 = *(const short8*)&sKl[base + ((quad + row) & 7) * 8];
            short8 kl1 = *(const short8*)&sKl[base + ((quad + 4 + row) & 7) * 8];
            s[j] = (floatx4){0.f, 0.f, 0.f, 0.f};
            s[j] = MFMA16(aqh[0], kh0, s[j]);
            s[j] = MFMA16(aqh[1], kh1, s[j]);
            s[j] = MFMA16(aql[0], kh0, s[j]);
            s[j] = MFMA16(aql[1], kh1, s[j]);
            s[j] = MFMA16(aqh[0], kl0, s[j]);
            s[j] = MFMA16(aqh[1], kl1, s[j]);
        }

        // ---- V fragments ----
        short8 gv0[4], gv1[4];
#pragma unroll
        for (int j2 = 0; j2 < 4; ++j2) {
            const int row = j2 * 16 + l15;
            const int base = row * 64;
            gv0[j2] = *(const short8*)&sV[base + ((quad + row) & 7) * 8];
            gv1[j2] = *(const short8*)&sV[base + ((quad + 4 + row) & 7) * 8];
        }

        // ---- exp, nt S store, P pack ----
#pragma unroll
        for (int j = 0; j < 4; ++j) {
#pragma unroll
            for (int r = 0; r < 4; ++r) {
                const float val = __expf(2.f * s[j][r] - q2v[r] - k2v[j]);
                const int row = q0 + 16 * w + quad * 4 + r;
                __builtin_nontemporal_store(val, &S[Sz + (size_t)row * 1024 + col0 + j * 16 + l15]);
                P[(16 * w + quad * 4 + r) * 72 + j * 16 + l15] = f2b_trunc(val);
            }
        }

        // ---- P readback (A-layout, wave-local) + S@V ----
        short8 pf0 = *(const short8*)&P[(16 * w + l15) * 72 + quad * 8];
        short8 pf1 = *(const short8*)&P[(16 * w + l15) * 72 + 32 + quad * 8];
#pragma unroll
        for (int j2 = 0; j2 < 4; ++j2) {
            oacc[j2] = MFMA16(pf0, gv0[j2], oacc[j2]);
            oacc[j2] = MFMA16(pf1, gv1[j2], oacc[j2]);
        }
        __syncthreads();
    }

#pragma unroll
    for (int j2 = 0; j2 < 4; ++j2)
#pragma unroll
        for (int r = 0; r < 4; ++r) {
            const int row = q0 + 16 * w + quad * 4 + r;
            attn[(size_t)(b * 1024 + row) * 512 + h * 64 + j2 * 16 + l15] =
                f2b(oacc[j2][r]);
        }
}

extern "C" void kernel_launch(void* const* d_in, const int* in_sizes, int n_in,
                              void* d_out, int out_size, void* d_ws, size_t ws_size,
                              hipStream_t stream)
{
    const float* query = (const float*)d_in[0];
    const float* key   = (const float*)d_in[1];
    const float* value = (const float*)d_in[2];
    const float* Wq    = (const float*)d_in[3];
    const float* Wk    = (const float*)d_in[4];
    const float* Wv    = (const float*)d_in[5];
    const float* Wo    = (const float*)d_in[6];

    float* out  = (float*)d_out;
    float* Sout = out + (size_t)8192 * 512;      // 268 MB

    const size_t NE = (size_t)8192 * 512;        // 4194304
    // Workspace (unchanged footprint ~52 MB):
    ushort_t* qh_hi   = (ushort_t*)d_ws;
    ushort_t* qh_lo   = qh_hi + NE;
    ushort_t* kh_hi   = qh_lo + NE;
    ushort_t* kh_lo   = kh_hi + NE;
    ushort_t* vhT     = kh_lo + NE;
    ushort_t* attn_bf = vhT + NE;
    ushort_t* WqT_hi  = attn_bf + NE;
    ushort_t* WqT_lo  = WqT_hi + 262144;
    ushort_t* WkT_hi  = WqT_lo + 262144;
    ushort_t* WkT_lo  = WkT_hi + 262144;
    ushort_t* WvT     = WkT_lo + 262144;
    ushort_t* WoT     = WvT + 262144;
    float*    q2      = (float*)(WoT + 262144);
    float*    k2      = q2 + 65536;

    // Pre-split scratch lives in the S output region (flash overwrites it).
    ushort_t* qxh = (ushort_t*)Sout;             // 5 x 8 MB = 40 MB << 268 MB
    ushort_t* qxl = qxh + NE;
    ushort_t* kxh = qxl + NE;
    ushort_t* kxl = kxh + NE;
    ushort_t* vx  = kxl + NE;

    wt_cvt<<<dim3(1024, 4), 256, 0, stream>>>(Wq, Wk, Wv, Wo, WqT_hi, WqT_lo,
                                              WkT_hi, WkT_lo, WvT, WoT);

    presplit<<<4096, 256, 0, stream>>>(query, key, value, qxh, qxl, kxh, kxl, vx);

    proj_all<<<3072, 256, 0, stream>>>(qxh, qxl, kxh, kxl, vx,
                                       WqT_hi, WqT_lo, WkT_hi, WkT_lo, WvT,
                                       qh_hi, qh_lo, kh_hi, kh_lo, vhT, q2, k2);

    flash_rbf<<<1024, 256, 0, stream>>>(qh_hi, qh_lo, kh_hi, kh_lo,
                                        vhT, q2, k2, Sout, attn_bf);

    outproj<<<1024, 256, 0, stream>>>(attn_bf, WoT, out);
}